// Round 1
// baseline (728.455 us; speedup 1.0000x reference)
//
#include <hip/hip_runtime.h>
#include <hip/hip_bf16.h>

#define NB 8
#define C1 256
#define HH 192
#define WW 192
#define GH 48
#define GW 48
#define NP 2304
#define KSEL 576
#define RH 64
#define HID 128
#define C4 1024
#define HW (HH*WW)

// ---- workspace layout (byte offsets) ----
#define WS_FLAG 0
#define WS_F 64
#define WS_POOLED 1129984ull
#define WS_SCORES 20004352ull
#define WS_SELIDX 20078080ull
#define WS_SELVAL 20096512ull
// float-index offsets inside F section (all 16B-aligned starts)
#define F_RW1 0
#define F_RG1 16384
#define F_RB1 16448
#define F_RW2 16512
#define F_RBIAS2 16576
#define F_EG1 16580
#define F_EB1 16708
#define F_DWW 16836
#define F_DWG 17988
#define F_DWB 18116
#define F_EG2 18244
#define F_EB2 19268
#define F_EW1 20292
#define F_EW2 151364
#define F_TOTAL 282436

__device__ __forceinline__ float b2f(unsigned short h) {
  return __uint_as_float(((unsigned)h) << 16);
}
__device__ __forceinline__ unsigned short f2b(float f) {
  unsigned u = __float_as_uint(f);
  u += 0x7FFF + ((u >> 16) & 1u);
  return (unsigned short)(u >> 16);
}
__device__ __forceinline__ float siluf(float v) { return v / (1.f + expf(-v)); }

// ---- dtype detector: bf16 buffer -> sane exponents at even u16 idx; fp32 -> garbage ----
__global__ void k_detect(const unsigned short* xb, char* ws) {
  __shared__ int cnt[256];
  int t = threadIdx.x;
  int c = 0;
  for (int s = 0; s < 32; ++s) {
    unsigned short u = xb[(t * 32 + s) * 2];
    int e = (u >> 7) & 0xFF;
    c += (u == 0 || (e >= 90 && e <= 145)) ? 1 : 0;
  }
  cnt[t] = c;
  __syncthreads();
  for (int s = 128; s > 0; s >>= 1) {
    if (t < s) cnt[t] += cnt[t + s];
    __syncthreads();
  }
  if (t == 0) *(int*)(ws + WS_FLAG) = (cnt[0] >= 4915) ? 1 : 0;  // 60% of 8192
}

// ---- convert all weights to fp32 into ws ----
__global__ void k_prep(const void* rw1, const void* rg1, const void* rb1, const void* rw2,
                       const void* rbias2, const void* ew1, const void* eg1, const void* eb1,
                       const void* dww, const void* dwg, const void* dwb, const void* ew2,
                       const void* eg2, const void* eb2, char* ws) {
  int bf = *(const int*)(ws + WS_FLAG);
  float* F = (float*)(ws + WS_F);
  int i = blockIdx.x * 256 + threadIdx.x;
  const void* src; int si; int dof;
  if      (i < 16384)  { src = rw1;    si = i;          dof = F_RW1 + si; }
  else if (i < 16448)  { src = rg1;    si = i - 16384;  dof = F_RG1 + si; }
  else if (i < 16512)  { src = rb1;    si = i - 16448;  dof = F_RB1 + si; }
  else if (i < 16576)  { src = rw2;    si = i - 16512;  dof = F_RW2 + si; }
  else if (i < 16577)  { src = rbias2; si = i - 16576;  dof = F_RBIAS2 + si; }
  else if (i < 147649) { src = ew1;    si = i - 16577;  dof = F_EW1 + si; }
  else if (i < 147777) { src = eg1;    si = i - 147649; dof = F_EG1 + si; }
  else if (i < 147905) { src = eb1;    si = i - 147777; dof = F_EB1 + si; }
  else if (i < 149057) { src = dww;    si = i - 147905; dof = F_DWW + si; }
  else if (i < 149185) { src = dwg;    si = i - 149057; dof = F_DWG + si; }
  else if (i < 149313) { src = dwb;    si = i - 149185; dof = F_DWB + si; }
  else if (i < 280385) { src = ew2;    si = i - 149313; dof = F_EW2 + si; }
  else if (i < 281409) { src = eg2;    si = i - 280385; dof = F_EG2 + si; }
  else if (i < 282433) { src = eb2;    si = i - 281409; dof = F_EB2 + si; }
  else return;
  float v = bf ? b2f(((const unsigned short*)src)[si]) : ((const float*)src)[si];
  F[dof] = v;
}

// ---- 4x4 avg pool: one thread per (b,c,py,px), coalesced along px ----
template<int BF>
__global__ void k_pool(const void* xin, char* ws) {
  if ((*(const int*)(ws + WS_FLAG) != 0) != (BF != 0)) return;
  float* pooled = (float*)(ws + WS_POOLED);
  int tid = blockIdx.x * 256 + threadIdx.x;  // grid exactly covers B*C1*GH*GW
  int px = tid % GW;
  int t2 = tid / GW;
  int py = t2 % GH;
  int bc = t2 / GH;
  size_t base = (size_t)bc * HW + (size_t)(py * 4) * WW + px * 4;
  float s = 0.f;
#pragma unroll
  for (int r = 0; r < 4; ++r) {
    if (BF) {
      const ushort4 v = *(const ushort4*)((const unsigned short*)xin + base + r * WW);
      s += b2f(v.x) + b2f(v.y) + b2f(v.z) + b2f(v.w);
    } else {
      const float4 v = *(const float4*)((const float*)xin + base + r * WW);
      s += v.x + v.y + v.z + v.w;
    }
  }
  pooled[tid] = s * 0.0625f;
}

// ---- router MLP -> sigmoid scores ----
__global__ void k_mlp(char* ws) {
  const float* F = (const float*)(ws + WS_F);
  const float* pooled = (const float*)(ws + WS_POOLED);
  float* scores = (float*)(ws + WS_SCORES);
  int pos = blockIdx.x * 256 + threadIdx.x;  // grid exactly covers B*NP
  int b = pos / NP, pp = pos % NP;
  const float* pb = pooled + (size_t)b * C1 * NP + pp;
  float acc[RH];
#pragma unroll
  for (int j = 0; j < RH; ++j) acc[j] = 0.f;
  for (int c = 0; c < C1; ++c) {
    float pv = pb[(size_t)c * NP];
    const float* wr = F + F_RW1 + c;
#pragma unroll
    for (int j = 0; j < RH; ++j) acc[j] += wr[j * C1] * pv;
  }
  const float BNS = 1.f / sqrtf(1.f + 1e-5f);
  float logit = F[F_RBIAS2];
#pragma unroll
  for (int j = 0; j < RH; ++j) {
    float v = acc[j] * (F[F_RG1 + j] * BNS) + F[F_RB1 + j];
    logit += F[F_RW2 + j] * siluf(v);
  }
  scores[pos] = 1.f / (1.f + expf(-logit));
}

// ---- exact top-k by rank (ties: lower index wins, matches lax.top_k) ----
__global__ void k_topk(char* ws) {
  const float* scores = (const float*)(ws + WS_SCORES);
  int* selidx = (int*)(ws + WS_SELIDX);
  float* selval = (float*)(ws + WS_SELVAL);
  int b = blockIdx.x / 9, r = blockIdx.x % 9;
  __shared__ float s[NP];
  for (int i = threadIdx.x; i < NP; i += 256) s[i] = scores[b * NP + i];
  __syncthreads();
  int i = r * 256 + threadIdx.x;
  float si = s[i];
  int rank = 0;
  for (int j = 0; j < NP; ++j) {
    float sj = s[j];
    rank += (sj > si || (sj == si && j < i)) ? 1 : 0;
  }
  if (rank < KSEL) {
    selidx[b * KSEL + rank] = i;
    selval[b * KSEL + rank] = si;
  }
}

// ---- zero-fill output (grid sized per dtype by host) ----
template<int BF>
__global__ void k_zero(void* out, const char* ws) {
  if ((*(const int*)(ws + WS_FLAG) != 0) != (BF != 0)) return;
  size_t i = (size_t)blockIdx.x * 256 + threadIdx.x;
  ((float4*)out)[i] = make_float4(0.f, 0.f, 0.f, 0.f);
}

// ---- expert: 4 patches per block ----
template<int BF>
__global__ __launch_bounds__(256) void k_expert(const void* xin, void* outv, char* ws) {
  if ((*(const int*)(ws + WS_FLAG) != 0) != (BF != 0)) return;
  const float* F = (const float*)(ws + WS_F);
  const int* selidx = (const int*)(ws + WS_SELIDX);
  const float* selval = (const float*)(ws + WS_SELVAL);
  __shared__ unsigned short uin[4][C4][4];  // pixel-unshuffled input, bf16
  __shared__ float y1[4][HID][4];
  __shared__ float y2[4][HID][4];
  __shared__ int sIdx[4];
  __shared__ float sVal[4];
  const float BNS = 1.f / sqrtf(1.f + 1e-5f);
  int t = threadIdx.x;
  int e0 = blockIdx.x * 4;
  if (t < 4) { sIdx[t] = selidx[e0 + t]; sVal[t] = selval[e0 + t]; }
  __syncthreads();
  int bb = e0 / KSEL;  // 576 % 4 == 0 -> block never straddles batches

  // phase A: gather + pixel_unshuffle into LDS
  {
    int g = t >> 6, lane = t & 63;
    int idx = sIdx[g];
    int py = idx / GW, px = idx % GW;
    size_t pbase = (size_t)bb * C1 * HW + (size_t)(py * 4) * WW + px * 4;
#pragma unroll
    for (int k = 0; k < 4; ++k) {
      int c = lane + 64 * k;
      size_t cb = pbase + (size_t)c * HW;
#pragma unroll
      for (int r = 0; r < 4; ++r) {
        unsigned short h0, h1, h2, h3;
        if (BF) {
          ushort4 u = *(const ushort4*)((const unsigned short*)xin + cb + r * WW);
          h0 = u.x; h1 = u.y; h2 = u.z; h3 = u.w;
        } else {
          float4 u = *(const float4*)((const float*)xin + cb + r * WW);
          h0 = f2b(u.x); h1 = f2b(u.y); h2 = f2b(u.z); h3 = f2b(u.w);
        }
        int pb2 = (r >> 1) * 2;           // p = (r>>1)*2 + (w>>1)
        int cb2 = c * 4 + (r & 1) * 2;    // ci = c*4 + (r&1)*2 + (w&1)
        uin[g][cb2 + 0][pb2 + 0] = h0;
        uin[g][cb2 + 1][pb2 + 0] = h1;
        uin[g][cb2 + 0][pb2 + 1] = h2;
        uin[g][cb2 + 1][pb2 + 1] = h3;
      }
    }
  }
  __syncthreads();

  // phase B: 1x1 conv 1024->128 + BN + SiLU (thread t: o = t&127, 2 patches)
  {
    int o = t & 127, gp = t >> 7;
    const float* w1 = F + F_EW1 + (size_t)o * C4;
    float a0[4] = {0, 0, 0, 0}, a1[4] = {0, 0, 0, 0};
    for (int ci = 0; ci < C4; ci += 4) {
      float4 w = *(const float4*)(w1 + ci);
      float wa[4] = {w.x, w.y, w.z, w.w};
#pragma unroll
      for (int u = 0; u < 4; ++u) {
        float wv = wa[u];
        ushort4 q0 = *(const ushort4*)&uin[gp * 2 + 0][ci + u][0];
        ushort4 q1 = *(const ushort4*)&uin[gp * 2 + 1][ci + u][0];
        a0[0] += wv * b2f(q0.x); a0[1] += wv * b2f(q0.y);
        a0[2] += wv * b2f(q0.z); a0[3] += wv * b2f(q0.w);
        a1[0] += wv * b2f(q1.x); a1[1] += wv * b2f(q1.y);
        a1[2] += wv * b2f(q1.z); a1[3] += wv * b2f(q1.w);
      }
    }
    float s1 = F[F_EG1 + o] * BNS, bb1 = F[F_EB1 + o];
#pragma unroll
    for (int p = 0; p < 4; ++p) {
      y1[gp * 2 + 0][o][p] = siluf(a0[p] * s1 + bb1);
      y1[gp * 2 + 1][o][p] = siluf(a1[p] * s1 + bb1);
    }
  }
  __syncthreads();

  // phase C: depthwise 3x3 (pad 1) on 2x2 + BN + SiLU
  {
    int ch = t & 127, gp = t >> 7;
    const float* kw = F + F_DWW + ch * 9;
    float k00 = kw[0], k01 = kw[1], k02 = kw[2];
    float k10 = kw[3], k11 = kw[4], k12 = kw[5];
    float k20 = kw[6], k21 = kw[7], k22 = kw[8];
    float sd = F[F_DWG + ch] * BNS, bd = F[F_DWB + ch];
#pragma unroll
    for (int gi = gp; gi < 4; gi += 2) {
      float i00 = y1[gi][ch][0], i01 = y1[gi][ch][1];
      float i10 = y1[gi][ch][2], i11 = y1[gi][ch][3];
      float o00 = k11 * i00 + k12 * i01 + k21 * i10 + k22 * i11;
      float o01 = k10 * i00 + k11 * i01 + k20 * i10 + k21 * i11;
      float o10 = k01 * i00 + k02 * i01 + k11 * i10 + k12 * i11;
      float o11 = k00 * i00 + k01 * i01 + k10 * i10 + k11 * i11;
      y2[gi][ch][0] = siluf(o00 * sd + bd);
      y2[gi][ch][1] = siluf(o01 * sd + bd);
      y2[gi][ch][2] = siluf(o10 * sd + bd);
      y2[gi][ch][3] = siluf(o11 * sd + bd);
    }
  }
  __syncthreads();

  // phase D: 1x1 conv 128->1024 + BN, *score, pixel_shuffle, scatter
  {
    for (int q = 0; q < 4; ++q) {
      int o2 = t + 256 * q;
      const float* w2 = F + F_EW2 + (size_t)o2 * HID;
      float acc[4][4];
#pragma unroll
      for (int g = 0; g < 4; ++g) acc[g][0] = acc[g][1] = acc[g][2] = acc[g][3] = 0.f;
      for (int h = 0; h < HID; h += 4) {
        float4 w = *(const float4*)(w2 + h);
        float wa[4] = {w.x, w.y, w.z, w.w};
#pragma unroll
        for (int u = 0; u < 4; ++u) {
#pragma unroll
          for (int g = 0; g < 4; ++g) {
            const float4 yv = *(const float4*)&y2[g][h + u][0];
            acc[g][0] += wa[u] * yv.x; acc[g][1] += wa[u] * yv.y;
            acc[g][2] += wa[u] * yv.z; acc[g][3] += wa[u] * yv.w;
          }
        }
      }
      float s2 = F[F_EG2 + o2] * BNS, b2v = F[F_EB2 + o2];
      int c = o2 >> 2, dr = (o2 >> 1) & 1, dc = o2 & 1;
#pragma unroll
      for (int g = 0; g < 4; ++g) {
        int idx = sIdx[g];
        int py = idx / GW, px = idx % GW;
        float val = sVal[g];
        size_t ob = ((size_t)(bb * C1 + c) * HH + py * 4 + dr) * WW + px * 4 + dc;
#pragma unroll
        for (int p = 0; p < 4; ++p) {
          int ii = p >> 1, jj = p & 1;
          float v = (acc[g][p] * s2 + b2v) * val;
          if (BF) ((unsigned short*)outv)[ob + ii * 2 * WW + jj * 2] = f2b(v);
          else    ((float*)outv)[ob + ii * 2 * WW + jj * 2] = v;
        }
      }
    }
  }
}

extern "C" void kernel_launch(void* const* d_in, const int* in_sizes, int n_in,
                              void* d_out, int out_size, void* d_ws, size_t ws_size,
                              hipStream_t stream) {
  char* ws = (char*)d_ws;
  const void* x = d_in[0];
  k_detect<<<1, 256, 0, stream>>>((const unsigned short*)x, ws);
  k_prep<<<1104, 256, 0, stream>>>(d_in[1], d_in[2], d_in[3], d_in[4], d_in[5], d_in[6],
                                   d_in[7], d_in[8], d_in[9], d_in[10], d_in[11], d_in[12],
                                   d_in[13], d_in[14], ws);
  k_pool<1><<<18432, 256, 0, stream>>>(x, ws);
  k_pool<0><<<18432, 256, 0, stream>>>(x, ws);
  k_mlp<<<72, 256, 0, stream>>>(ws);
  k_topk<<<72, 256, 0, stream>>>(ws);
  // out bytes / 16 per thread: bf16 -> 9,437,184 threads; fp32 -> 18,874,368
  k_zero<1><<<36864, 256, 0, stream>>>(d_out, ws);
  k_zero<0><<<73728, 256, 0, stream>>>(d_out, ws);
  k_expert<1><<<1152, 256, 0, stream>>>(x, d_out, ws);
  k_expert<0><<<1152, 256, 0, stream>>>(x, d_out, ws);
}

// Round 2
// 610.401 us; speedup vs baseline: 1.1934x; 1.1934x over previous
//
#include <hip/hip_runtime.h>
#include <hip/hip_bf16.h>

typedef __attribute__((ext_vector_type(8))) short bf16x8;
typedef __attribute__((ext_vector_type(4))) float f32x4;

#define NB 8
#define C1 256
#define HH 192
#define WW 192
#define GH 48
#define GW 48
#define NP 2304
#define KSEL 576
#define RH 64
#define HID 128
#define C4 1024
#define HW (HH*WW)

// ---- workspace layout (byte offsets) ----
#define WS_FLAG 0
#define WS_F 64
#define WS_W16 81280ull
#define WS_POOLED 605696ull
#define WS_PSCALE WS_POOLED   /* pooled dead after k_mlp; reuse for pscale */
#define WS_SCORES 19480064ull

// ---- float-index offsets inside F section ----
#define F_RW1 0
#define F_RG1 16384
#define F_RB1 16448
#define F_RW2 16512
#define F_RBIAS2 16576
#define F_EG1 16580
#define F_EB1 16708
#define F_DWW 16836
#define F_DWG 17988
#define F_DWB 18116
#define F_EG2 18244
#define F_EB2 19268

__device__ __forceinline__ float b2f(unsigned short h) {
  return __uint_as_float(((unsigned)h) << 16);
}
__device__ __forceinline__ unsigned short f2b(float f) {
  unsigned u = __float_as_uint(f);
  u += 0x7FFF + ((u >> 16) & 1u);
  return (unsigned short)(u >> 16);
}
__device__ __forceinline__ float siluf(float v) { return v / (1.f + expf(-v)); }

// ---- dtype detector ----
__global__ void k_detect(const unsigned short* xb, char* ws) {
  __shared__ int cnt[256];
  int t = threadIdx.x;
  int c = 0;
  for (int s = 0; s < 32; ++s) {
    unsigned short u = xb[(t * 32 + s) * 2];
    int e = (u >> 7) & 0xFF;
    c += (u == 0 || (e >= 90 && e <= 145)) ? 1 : 0;
  }
  cnt[t] = c;
  __syncthreads();
  for (int s = 128; s > 0; s >>= 1) {
    if (t < s) cnt[t] += cnt[t + s];
    __syncthreads();
  }
  if (t == 0) *(int*)(ws + WS_FLAG) = (cnt[0] >= 4915) ? 1 : 0;
}

// ---- weight prep: fp32 params into F, expert 1x1 weights into bf16 ----
__global__ void k_prep(const void* rw1, const void* rg1, const void* rb1, const void* rw2,
                       const void* rbias2, const void* ew1, const void* eg1, const void* eb1,
                       const void* dww, const void* dwg, const void* dwb, const void* ew2,
                       const void* eg2, const void* eb2, char* ws) {
  int bf = *(const int*)(ws + WS_FLAG);
  float* F = (float*)(ws + WS_F);
  unsigned short* W16 = (unsigned short*)(ws + WS_W16);
  int i = blockIdx.x * 256 + threadIdx.x;
  if (i >= 282433) return;
  if (i < 20289) {  // fp32 section
    const void* src; int si; int dof;
    if      (i < 16384) { src = rw1;    si = i;          dof = F_RW1 + si; }
    else if (i < 16448) { src = rg1;    si = i - 16384;  dof = F_RG1 + si; }
    else if (i < 16512) { src = rb1;    si = i - 16448;  dof = F_RB1 + si; }
    else if (i < 16576) { src = rw2;    si = i - 16512;  dof = F_RW2 + si; }
    else if (i < 16577) { src = rbias2; si = i - 16576;  dof = F_RBIAS2 + si; }
    else if (i < 16705) { src = eg1;    si = i - 16577;  dof = F_EG1 + si; }
    else if (i < 16833) { src = eb1;    si = i - 16705;  dof = F_EB1 + si; }
    else if (i < 17985) { src = dww;    si = i - 16833;  dof = F_DWW + si; }
    else if (i < 18113) { src = dwg;    si = i - 17985;  dof = F_DWG + si; }
    else if (i < 18241) { src = dwb;    si = i - 18113;  dof = F_DWB + si; }
    else if (i < 19265) { src = eg2;    si = i - 18241;  dof = F_EG2 + si; }
    else                { src = eb2;    si = i - 19265;  dof = F_EB2 + si; }
    F[dof] = bf ? b2f(((const unsigned short*)src)[si]) : ((const float*)src)[si];
  } else {          // bf16 weight section: W1b then W2b
    int j = i - 20289;
    const void* src; int si; int dof;
    if (j < 131072) { src = ew1; si = j;          dof = j; }
    else            { src = ew2; si = j - 131072; dof = j; }
    W16[dof] = bf ? ((const unsigned short*)src)[si]
                  : f2b(((const float*)src)[si]);
  }
}

// ---- 4x4 avg pool (unchanged from passing round -> identical selection) ----
template<int BF>
__global__ void k_pool(const void* xin, char* ws) {
  if ((*(const int*)(ws + WS_FLAG) != 0) != (BF != 0)) return;
  float* pooled = (float*)(ws + WS_POOLED);
  int tid = blockIdx.x * 256 + threadIdx.x;
  int px = tid % GW;
  int t2 = tid / GW;
  int py = t2 % GH;
  int bc = t2 / GH;
  size_t base = (size_t)bc * HW + (size_t)(py * 4) * WW + px * 4;
  float s = 0.f;
#pragma unroll
  for (int r = 0; r < 4; ++r) {
    if (BF) {
      const ushort4 v = *(const ushort4*)((const unsigned short*)xin + base + r * WW);
      s += b2f(v.x) + b2f(v.y) + b2f(v.z) + b2f(v.w);
    } else {
      const float4 v = *(const float4*)((const float*)xin + base + r * WW);
      s += v.x + v.y + v.z + v.w;
    }
  }
  pooled[tid] = s * 0.0625f;
}

// ---- router MLP -> sigmoid scores (unchanged) ----
__global__ void k_mlp(char* ws) {
  const float* F = (const float*)(ws + WS_F);
  const float* pooled = (const float*)(ws + WS_POOLED);
  float* scores = (float*)(ws + WS_SCORES);
  int pos = blockIdx.x * 256 + threadIdx.x;
  int b = pos / NP, pp = pos % NP;
  const float* pb = pooled + (size_t)b * C1 * NP + pp;
  float acc[RH];
#pragma unroll
  for (int j = 0; j < RH; ++j) acc[j] = 0.f;
  for (int c = 0; c < C1; ++c) {
    float pv = pb[(size_t)c * NP];
    const float* wr = F + F_RW1 + c;
#pragma unroll
    for (int j = 0; j < RH; ++j) acc[j] += wr[j * C1] * pv;
  }
  const float BNS = 1.f / sqrtf(1.f + 1e-5f);
  float logit = F[F_RBIAS2];
#pragma unroll
  for (int j = 0; j < RH; ++j) {
    float v = acc[j] * (F[F_RG1 + j] * BNS) + F[F_RB1 + j];
    logit += F[F_RW2 + j] * siluf(v);
  }
  scores[pos] = 1.f / (1.f + expf(-logit));
}

// ---- per-patch scale: score if in top-k else 0 (rank logic identical) ----
__global__ void k_route(char* ws) {
  const float* scores = (const float*)(ws + WS_SCORES);
  float* pscale = (float*)(ws + WS_PSCALE);
  int b = blockIdx.x / 9, r = blockIdx.x % 9;
  __shared__ float s[NP];
  for (int i = threadIdx.x; i < NP; i += 256) s[i] = scores[b * NP + i];
  __syncthreads();
  int i = r * 256 + threadIdx.x;
  float si = s[i];
  int rank = 0;
  for (int j = 0; j < NP; ++j) {
    float sj = s[j];
    rank += (sj > si || (sj == si && j < i)) ? 1 : 0;
  }
  pscale[b * NP + i] = (rank < KSEL) ? si : 0.f;
}

// ---- dense expert: all patches, MFMA GEMMs, coalesced full-output write ----
template<int BF>
__global__ __launch_bounds__(512, 4) void k_expert(const void* xin, void* outv, char* ws) {
  if ((*(const int*)(ws + WS_FLAG) != 0) != (BF != 0)) return;
  const float* F = (const float*)(ws + WS_F);
  const unsigned short* W1b = (const unsigned short*)(ws + WS_W16);
  const unsigned short* W2b = W1b + 131072;
  const float* pscale = (const float*)(ws + WS_PSCALE);

  __shared__ __align__(16) unsigned short UT[64 * 72];   // [n][k64+8] bf16, 9216 B
  __shared__ __align__(16) unsigned short WC[128 * 72];  // g1: [m128][k64+8]; g2: [m64][k128+8]
  __shared__ __align__(16) float O1[128 * 68];           // g1 out / g2 out tile, 34816 B
  __shared__ __align__(16) unsigned short Y2T[64 * 136]; // [n][h128+8] bf16, 17408 B
  __shared__ float PS[16];

  const int t = threadIdx.x;
  const int lane = t & 63;
  const int w = t >> 6;             // wave 0..7
  const int wm = w >> 2, wn = w & 3;
  const int l15 = lane & 15, l4 = lane >> 4;
  const int bid = blockIdx.x;
  const int xq = bid % 3;
  const int py = (bid / 3) % GH;
  const int b  = bid / (3 * GH);
  const int r0 = py * 4, c0 = xq * 64;
  const float BNS = 1.f / sqrtf(1.f + 1e-5f);

  if (t < 16) PS[t] = pscale[b * NP + py * GW + xq * 16 + t];

  // ---- staging coordinates ----
  const int rr = (t >> 4) & 3, v4 = t & 15;
  const int n0 = v4 * 4 + (rr >> 1) * 2;
  const int kb0 = w * 4 + (rr & 1) * 2;
  const int kb1 = (w + 8) * 4 + (rr & 1) * 2;
  const size_t xoff0 = ((size_t)(b * C1) + w) * HW + (size_t)(r0 + rr) * WW + c0 + v4 * 4;
  const size_t xoff1 = xoff0 + (size_t)8 * HW;
  const int m_0 = t >> 3, k8_0 = t & 7;
  const float* xf = (const float*)xin;
  const unsigned short* xh = (const unsigned short*)xin;

  float4 xf_r[2][2];
  ushort4 xh_r[2][2];
  uint4 w_r[2][2];

  auto xload = [&](int buf, int cc) {
    size_t o = (size_t)cc * 16 * HW;
    if (BF) {
      xh_r[buf][0] = *(const ushort4*)(xh + xoff0 + o);
      xh_r[buf][1] = *(const ushort4*)(xh + xoff1 + o);
    } else {
      xf_r[buf][0] = *(const float4*)(xf + xoff0 + o);
      xf_r[buf][1] = *(const float4*)(xf + xoff1 + o);
    }
    const unsigned short* wp = W1b + cc * 64;
    w_r[buf][0] = *(const uint4*)(wp + m_0 * 1024 + k8_0 * 8);
    w_r[buf][1] = *(const uint4*)(wp + (m_0 + 64) * 1024 + k8_0 * 8);
  };
  auto xwrite = [&](int buf) {
    unsigned lo0, hi0, lo1, hi1;
    if (BF) {
      lo0 = xh_r[buf][0].x | ((unsigned)xh_r[buf][0].y << 16);
      hi0 = xh_r[buf][0].z | ((unsigned)xh_r[buf][0].w << 16);
      lo1 = xh_r[buf][1].x | ((unsigned)xh_r[buf][1].y << 16);
      hi1 = xh_r[buf][1].z | ((unsigned)xh_r[buf][1].w << 16);
    } else {
      lo0 = f2b(xf_r[buf][0].x) | ((unsigned)f2b(xf_r[buf][0].y) << 16);
      hi0 = f2b(xf_r[buf][0].z) | ((unsigned)f2b(xf_r[buf][0].w) << 16);
      lo1 = f2b(xf_r[buf][1].x) | ((unsigned)f2b(xf_r[buf][1].y) << 16);
      hi1 = f2b(xf_r[buf][1].z) | ((unsigned)f2b(xf_r[buf][1].w) << 16);
    }
    *(unsigned*)&UT[n0 * 72 + kb0] = lo0;
    *(unsigned*)&UT[(n0 + 1) * 72 + kb0] = hi0;
    *(unsigned*)&UT[n0 * 72 + kb1] = lo1;
    *(unsigned*)&UT[(n0 + 1) * 72 + kb1] = hi1;
    *(uint4*)&WC[m_0 * 72 + k8_0 * 8] = w_r[buf][0];
    *(uint4*)&WC[(m_0 + 64) * 72 + k8_0 * 8] = w_r[buf][1];
  };

  // ---- GEMM1: [128 x 1024] x [1024 x 64] over 16 chunks of K=64 ----
  f32x4 acc1[4];
#pragma unroll
  for (int mi = 0; mi < 4; ++mi) acc1[mi] = (f32x4){0.f, 0.f, 0.f, 0.f};

  xload(0, 0);
  xload(1, 1);
#pragma unroll
  for (int cc = 0; cc < 16; ++cc) {
    __syncthreads();                 // prior chunk's readers done
    xwrite(cc & 1);                  // regs -> LDS (waits loads)
    __syncthreads();                 // LDS visible
    if (cc < 14) xload(cc & 1, cc + 2);
#pragma unroll
    for (int ks = 0; ks < 2; ++ks) {
      bf16x8 bfrag = *(const bf16x8*)&UT[(16 * wn + l15) * 72 + ks * 32 + l4 * 8];
#pragma unroll
      for (int mi = 0; mi < 4; ++mi) {
        bf16x8 afrag = *(const bf16x8*)&WC[(64 * wm + 16 * mi + l15) * 72 + ks * 32 + l4 * 8];
        acc1[mi] = __builtin_amdgcn_mfma_f32_16x16x32_bf16(afrag, bfrag, acc1[mi], 0, 0, 0);
      }
    }
  }

  // GEMM1 epilogue: BN + SiLU -> O1[h][n]
#pragma unroll
  for (int mi = 0; mi < 4; ++mi) {
#pragma unroll
    for (int r = 0; r < 4; ++r) {
      int h = 64 * wm + 16 * mi + l4 * 4 + r;
      float s1 = F[F_EG1 + h] * BNS, b1 = F[F_EB1 + h];
      O1[h * 68 + 16 * wn + l15] = siluf(acc1[mi][r] * s1 + b1);
    }
  }
  __syncthreads();

  // ---- depthwise 3x3 on 2x2 + BN + SiLU -> Y2T[n][h] (bf16) ----
#pragma unroll
  for (int s = 0; s < 4; ++s) {
    int id = t + 512 * s;
    int h = id & 127, p = id >> 7;
    float4 v = *(const float4*)&O1[h * 68 + p * 4];
    const float* kw = F + F_DWW + h * 9;
    float sd = F[F_DWG + h] * BNS, bd = F[F_DWB + h];
    float o00 = kw[4] * v.x + kw[5] * v.y + kw[7] * v.z + kw[8] * v.w;
    float o01 = kw[3] * v.x + kw[4] * v.y + kw[6] * v.z + kw[7] * v.w;
    float o10 = kw[1] * v.x + kw[2] * v.y + kw[4] * v.z + kw[5] * v.w;
    float o11 = kw[0] * v.x + kw[1] * v.y + kw[3] * v.z + kw[4] * v.w;
    Y2T[(p * 4 + 0) * 136 + h] = f2b(siluf(o00 * sd + bd));
    Y2T[(p * 4 + 1) * 136 + h] = f2b(siluf(o01 * sd + bd));
    Y2T[(p * 4 + 2) * 136 + h] = f2b(siluf(o10 * sd + bd));
    Y2T[(p * 4 + 3) * 136 + h] = f2b(siluf(o11 * sd + bd));
  }
  __syncthreads();

  // ---- GEMM2: [1024 x 128] x [128 x 64], 16 tiles of 64 rows ----
  bf16x8 bq[4];
#pragma unroll
  for (int ks = 0; ks < 4; ++ks)
    bq[ks] = *(const bf16x8*)&Y2T[(16 * wn + l15) * 136 + ks * 32 + l4 * 8];

  const int m2a = t >> 4, kk8 = t & 15;
  uint4 w2r[2][2];
  auto w2load = [&](int buf, int mt) {
    const unsigned short* wp = W2b + (size_t)mt * 8192;
    w2r[buf][0] = *(const uint4*)(wp + (size_t)t * 8);
    w2r[buf][1] = *(const uint4*)(wp + (size_t)(t + 512) * 8);
  };

  const int o_rr = (t >> 4) & 3, o_v4 = t & 15, o_cl = t >> 6;

  w2load(0, 0);
  w2load(1, 1);
#pragma unroll
  for (int mt = 0; mt < 16; ++mt) {
    __syncthreads();                 // prev tile's WC/O1 readers done
    *(uint4*)&WC[m2a * 136 + kk8 * 8] = w2r[mt & 1][0];
    *(uint4*)&WC[(m2a + 32) * 136 + kk8 * 8] = w2r[mt & 1][1];
    __syncthreads();
    if (mt < 14) w2load(mt & 1, mt + 2);

    f32x4 acc2[2];
    acc2[0] = (f32x4){0.f, 0.f, 0.f, 0.f};
    acc2[1] = (f32x4){0.f, 0.f, 0.f, 0.f};
#pragma unroll
    for (int ks = 0; ks < 4; ++ks) {
#pragma unroll
      for (int mi = 0; mi < 2; ++mi) {
        bf16x8 afrag = *(const bf16x8*)&WC[(32 * wm + 16 * mi + l15) * 136 + ks * 32 + l4 * 8];
        acc2[mi] = __builtin_amdgcn_mfma_f32_16x16x32_bf16(afrag, bq[ks], acc2[mi], 0, 0, 0);
      }
    }
    // epilogue: BN -> O1 (as O2 tile buffer [64][68])
#pragma unroll
    for (int mi = 0; mi < 2; ++mi) {
#pragma unroll
      for (int r = 0; r < 4; ++r) {
        int mloc = 32 * wm + 16 * mi + l4 * 4 + r;
        int m2 = mt * 64 + mloc;
        float s2 = F[F_EG2 + m2] * BNS, b2 = F[F_EB2 + m2];
        O1[mloc * 68 + 16 * wn + l15] = acc2[mi][r] * s2 + b2;
      }
    }
    __syncthreads();
    // store: pixel_shuffle + *pscale, fully coalesced float4/ushort4
#pragma unroll
    for (int s = 0; s < 2; ++s) {
      int cl = o_cl + 8 * s;
      int ch = mt * 16 + cl;
      size_t ob = ((size_t)(b * C1 + ch) * HH + r0 + o_rr) * WW + c0 + o_v4 * 4;
      int nn = o_v4 * 4 + (o_rr >> 1) * 2;
      int hb = cl * 4 + (o_rr & 1) * 2;
      float ps = PS[o_v4];
      float e0 = O1[(hb + 0) * 68 + nn] * ps;
      float e1 = O1[(hb + 1) * 68 + nn] * ps;
      float e2 = O1[(hb + 0) * 68 + nn + 1] * ps;
      float e3 = O1[(hb + 1) * 68 + nn + 1] * ps;
      if (BF) {
        ushort4 o4 = {f2b(e0), f2b(e1), f2b(e2), f2b(e3)};
        *(ushort4*)((unsigned short*)outv + ob) = o4;
      } else {
        float4 o4 = {e0, e1, e2, e3};
        *(float4*)((float*)outv + ob) = o4;
      }
    }
  }
}

extern "C" void kernel_launch(void* const* d_in, const int* in_sizes, int n_in,
                              void* d_out, int out_size, void* d_ws, size_t ws_size,
                              hipStream_t stream) {
  char* ws = (char*)d_ws;
  const void* x = d_in[0];
  k_detect<<<1, 256, 0, stream>>>((const unsigned short*)x, ws);
  k_prep<<<1104, 256, 0, stream>>>(d_in[1], d_in[2], d_in[3], d_in[4], d_in[5], d_in[6],
                                   d_in[7], d_in[8], d_in[9], d_in[10], d_in[11], d_in[12],
                                   d_in[13], d_in[14], ws);
  k_pool<1><<<18432, 256, 0, stream>>>(x, ws);
  k_pool<0><<<18432, 256, 0, stream>>>(x, ws);
  k_mlp<<<72, 256, 0, stream>>>(ws);
  k_route<<<72, 256, 0, stream>>>(ws);
  k_expert<1><<<1152, 512, 0, stream>>>(x, d_out, ws);
  k_expert<0><<<1152, 512, 0, stream>>>(x, d_out, ws);
}